// Round 17
// baseline (107.692 us; speedup 1.0000x reference)
//
#include <hip/hip_runtime.h>

// SelfAttention fwd: qkv GEMM -> causal flash attention (kv-split 2-pass) ->
// proj GEMM, bf16 MFMA.  B=8 T=1024 C=768 H=12 HD=64.
// Round-17: attn was resident-block-starved (768 blocks, occ 21%, tail drain).
// KV-split-2: each (bh,qt) block pair handles HALF the kv range (qt+1 tiles
// each -- exactly balanced), writes normalized partial O (bf16) + m,l (fp32);
// a ~38MB elementwise merge combines. Wave micro-structure unchanged.
// Falls back to the proven single-pass attn if ws_size < 81.8MB.

typedef unsigned short u16;
typedef unsigned int u32;
typedef __bf16 bf16x8 __attribute__((ext_vector_type(8)));
typedef float  f32x4  __attribute__((ext_vector_type(4)));
typedef float  f32x16 __attribute__((ext_vector_type(16)));
typedef unsigned short u16x4 __attribute__((ext_vector_type(4)));
typedef unsigned short u16x8 __attribute__((ext_vector_type(8)));
typedef unsigned int u32x4 __attribute__((ext_vector_type(4)));

#define DEV static __device__ __forceinline__

constexpr int B_ = 8, T_ = 1024, C_ = 768, H_ = 12, HD_ = 64;
constexpr int M1 = B_ * T_;   // 8192
constexpr int N1 = 3 * C_;    // 2304
constexpr int KD = C_;        // 768
constexpr int NROW = B_ * H_ * T_;  // 98304

DEV u16 f2bf(float f) {
    union { float f; unsigned u; } v; v.f = f;
    unsigned r = v.u + 0x7fffu + ((v.u >> 16) & 1u);   // RNE
    return (u16)(r >> 16);
}

DEV u16 bfbits(float f) {
    __bf16 h = (__bf16)f;
    union { __bf16 h; u16 u; } v; v.h = h;
    return v.u;
}

DEV float bf2f(u16 x) {
    union { u32 u; float f; } v; v.u = (u32)x << 16;
    return v.f;
}

DEV u32 cvtpk(float lo, float hi) {  // pack 2 f32 -> 2 bf16 (RNE), one instr
    u32 r;
    asm("v_cvt_pk_bf16_f32 %0, %1, %2" : "=v"(r) : "v"(lo), "v"(hi));
    return r;
}

DEV void gload16(const void* g, void* l) {
    __builtin_amdgcn_global_load_lds(
        (const __attribute__((address_space(1))) unsigned*)g,
        (__attribute__((address_space(3))) unsigned*)l, 16, 0, 0);
}

DEV float redmax16(f32x16 v) {
    float a0 = fmaxf(v[0], v[1]), a1 = fmaxf(v[2], v[3]);
    float a2 = fmaxf(v[4], v[5]), a3 = fmaxf(v[6], v[7]);
    float a4 = fmaxf(v[8], v[9]), a5 = fmaxf(v[10], v[11]);
    float a6 = fmaxf(v[12], v[13]), a7 = fmaxf(v[14], v[15]);
    float b0 = fmaxf(a0, a1), b1 = fmaxf(a2, a3);
    float b2 = fmaxf(a4, a5), b3 = fmaxf(a6, a7);
    return fmaxf(fmaxf(b0, b1), fmaxf(b2, b3));
}
DEV float redsum16(f32x16 v) {
    float a0 = v[0] + v[1], a1 = v[2] + v[3], a2 = v[4] + v[5], a3 = v[6] + v[7];
    float a4 = v[8] + v[9], a5 = v[10] + v[11], a6 = v[12] + v[13], a7 = v[14] + v[15];
    float b0 = a0 + a1, b1 = a2 + a3, b2 = a4 + a5, b3 = a6 + a7;
    return (b0 + b1) + (b2 + b3);
}

// ---------------- merged convert kernel ----------------

__global__ __launch_bounds__(256) void cvt_all_kern(
    const float* __restrict__ x, u16* __restrict__ xb,
    const float* __restrict__ Wq, const float* __restrict__ Wp,
    u16* __restrict__ WqT, u16* __restrict__ WpT) {
    __shared__ float tile[32][33];
    const int bid = blockIdx.x;
    if (bid < 3072) {  // x-convert: 3072*256*8 = M1*C_ elements exactly
        const int i = bid * 256 + threadIdx.x;
        const float4* xf = (const float4*)x;
        float4 a = xf[i * 2], b = xf[i * 2 + 1];
        u16x8 o;
        o[0] = f2bf(a.x); o[1] = f2bf(a.y); o[2] = f2bf(a.z); o[3] = f2bf(a.w);
        o[4] = f2bf(b.x); o[5] = f2bf(b.y); o[6] = f2bf(b.z); o[7] = f2bf(b.w);
        *(u16x8*)(xb + (size_t)i * 8) = o;
        return;
    }
    const int wb = bid - 3072;
    int bx = wb % 96;
    const int k0 = (wb / 96) * 32;
    const float* W; u16* Wt; int N;
    if (bx < N1 / 32) { W = Wq; Wt = WqT; N = N1; }
    else { bx -= N1 / 32; W = Wp; Wt = WpT; N = C_; }
    const int n0 = bx * 32;
    const int tx = threadIdx.x & 31, ty = threadIdx.x >> 5;  // 32 x 8
#pragma unroll
    for (int i = 0; i < 4; i++) {
        int k = ty * 4 + i;
        tile[k][tx] = W[(size_t)(k0 + k) * N + n0 + tx];
    }
    __syncthreads();
#pragma unroll
    for (int i = 0; i < 4; i++) {
        int n = ty * 4 + i;
        Wt[(size_t)(n0 + n) * KD + k0 + tx] = f2bf(tile[tx][n]);
    }
}

// ---------------- GEMM (A [M][K] bf16, Bt [N][K] bf16) ----------------
// Best-measured config (gemm0 41.5us): 128x128 tile, BK=64, single-buffer
// 32KB LDS, 2 barriers/K-step. XCD-chunked bijective block swizzle.
// MODE 0: qkv epilogue via LDS re-tile. q scaled 0.125*log2e (exp2 softmax).
// MODE 1: fp32 out + bias.

template <int MODE>
__global__ __launch_bounds__(256, 2) void gemm_bt_kern(
    const u16* __restrict__ A, const u16* __restrict__ Bt,
    const float* __restrict__ bias, int nBN,
    u16* __restrict__ qw, u16* __restrict__ kw, u16* __restrict__ vw,
    float* __restrict__ out) {
    __shared__ u16 lds[16384];          // 32KB: A-tile 16KB + B-tile 16KB
    char* LA = (char*)lds;
    char* LB = (char*)lds + 16384;
    const int cpx = gridDim.x >> 3;
    const int bid = (blockIdx.x & 7) * cpx + (blockIdx.x >> 3);
    const int bm = bid / nBN, bn = bid % nBN;
    const int m0 = bm * 128, n0 = bn * 128;
    const int t = threadIdx.x;
    const int lane = t & 63, w = t >> 6;
    const int wr = w >> 1, wc = w & 1;
    const int l15 = lane & 15, lhi = lane >> 4;
    const int srow = t >> 3;
    const int scb = ((t & 7) << 4) ^ ((srow & 7) << 4);  // pre-swizzled chunk
    const char* Ab = (const char*)(A + (size_t)(m0 + srow) * KD) + scb;
    const char* Bb = (const char*)(Bt + (size_t)(n0 + srow) * KD) + scb;

    f32x4 acc[4][4] = {};

    for (int k0 = 0; k0 < KD; k0 += 64) {
#pragma unroll
        for (int s = 0; s < 4; s++) {
            gload16(Ab + (size_t)k0 * 2 + (size_t)s * 32 * KD * 2, LA + w * 1024 + s * 4096);
            gload16(Bb + (size_t)k0 * 2 + (size_t)s * 32 * KD * 2, LB + w * 1024 + s * 4096);
        }
        __syncthreads();
#pragma unroll
        for (int kk = 0; kk < 2; kk++) {
            bf16x8 af[4], bfr[4];
#pragma unroll
            for (int i = 0; i < 4; i++) {
                int rowA = wr * 64 + i * 16 + l15;
                af[i] = *(const bf16x8*)(LA + rowA * 128 +
                                         ((kk * 64 + lhi * 16) ^ ((rowA & 7) << 4)));
                int rowB = wc * 64 + i * 16 + l15;
                bfr[i] = *(const bf16x8*)(LB + rowB * 128 +
                                          ((kk * 64 + lhi * 16) ^ ((rowB & 7) << 4)));
            }
#pragma unroll
            for (int fm = 0; fm < 4; fm++)
#pragma unroll
                for (int fn = 0; fn < 4; fn++)
                    acc[fm][fn] = __builtin_amdgcn_mfma_f32_16x16x32_bf16(
                        af[fm], bfr[fn], acc[fm][fn], 0, 0, 0);
        }
        __syncthreads();
    }

    if constexpr (MODE == 1) {
#pragma unroll
        for (int fm = 0; fm < 4; fm++) {
            const int mb = m0 + wr * 64 + fm * 16 + lhi * 4;
#pragma unroll
            for (int fn = 0; fn < 4; fn++) {
                const int n = n0 + wc * 64 + fn * 16 + l15;
                const float bv = bias[n];
#pragma unroll
                for (int r = 0; r < 4; r++)
                    out[(size_t)(mb + r) * C_ + n] = acc[fm][fn][r] + bv;
            }
        }
    } else {
        char* TT = (char*)lds;          // 128x128 bf16 = 32KB
        const int typ = bn / 6;         // 0=q, 1=k, 2=v
        const int h0 = (bn % 6) * 2;    // first head covered by this tile
        if (typ < 2) {
            const float sc = (typ == 0) ? 0.125f * 1.44269504f : 1.0f;
#pragma unroll
            for (int fn = 0; fn < 4; fn++) {
                const int col = wc * 64 + fn * 16 + l15;
                const float bv = bias[n0 + col];
#pragma unroll
                for (int fm = 0; fm < 4; fm++) {
                    const int row0 = wr * 64 + fm * 16 + lhi * 4;
#pragma unroll
                    for (int r = 0; r < 4; r++) {
                        const int row = row0 + r;
                        *(u16*)(TT + row * 256 + ((col * 2) ^ ((row & 7) << 5))) =
                            bfbits((acc[fm][fn][r] + bv) * sc);
                    }
                }
            }
            __syncthreads();
            u16* dst = (typ == 0) ? qw : kw;
#pragma unroll
            for (int i = 0; i < 8; i++) {
                const int wk = t + 256 * i;
                const int m = wk >> 4, c = wk & 15;
                u16x8 v8 = *(u16x8*)(TT + m * 256 + ((c * 16) ^ ((m & 7) << 5)));
                const int mb = m0 + m, b = mb >> 10, tq = mb & 1023;
                const int h = h0 + (c >> 3), d0 = (c & 7) * 8;
                *(u16x8*)(dst + (((size_t)(b * H_ + h) * T_ + tq) << 6) + d0) = v8;
            }
        } else {
#pragma unroll
            for (int fn = 0; fn < 4; fn++) {
                const int col = wc * 64 + fn * 16 + l15;
                const float bv = bias[n0 + col];
                const int cx = (col & 7) << 4;
#pragma unroll
                for (int fm = 0; fm < 4; fm++) {
                    const int row0 = wr * 64 + fm * 16 + lhi * 4;
                    u16x4 pk;
#pragma unroll
                    for (int r = 0; r < 4; r++) pk[r] = bfbits(acc[fm][fn][r] + bv);
                    *(u16x4*)(TT + col * 256 + ((row0 * 2) ^ cx)) = pk;
                }
            }
            __syncthreads();
#pragma unroll
            for (int i = 0; i < 8; i++) {
                const int wk = t + 256 * i;
                const int col = wk >> 4, ch = wk & 15;
                u16x8 v8 = *(u16x8*)(TT + col * 256 + ((ch * 16) ^ ((col & 7) << 4)));
                const int b = m0 >> 10, tq0 = (m0 & 1023) + ch * 8;
                const int h = h0 + (col >> 6), d = col & 63;
                *(u16x8*)(vw + (((size_t)(b * H_ + h) * HD_ + d) << 10) + tq0) = v8;
            }
        }
    }
}

// ---------------- causal flash attention (swapped 32x32 MFMA) ----------------
// Wave micro-structure = best-measured R14: 256 thr / 4 waves, 32 q-rows/wave,
// KVBLK=64, dbuf LDS K/V, swapped QK^T, lane-local exp2 softmax, in-reg P
// (cvt_pk+permlane32_swap), defer-max.
// SPLIT=0: single-pass, kv range [0, 2qt+2), writes ao directly (grid 768).
// SPLIT=1: kv-split-2, block handles half the range (qt+1 tiles; s=1 gets the
//          diagonal half), writes normalized partial O (bf16, [B,H,T,64]) and
//          m,l (fp32) for the merge pass (grid 1536).

template <int SPLIT>
__global__ __launch_bounds__(256, 4) void attn_fwd_kern(
    const u16* __restrict__ qg, const u16* __restrict__ kg,
    const u16* __restrict__ vg, u16* __restrict__ ao,
    u16* __restrict__ On0, u16* __restrict__ On1, float* __restrict__ ml) {
    __shared__ u16 kld[2][64 * 64];
    __shared__ u16 vld[2][64 * 64];
    const int n = blockIdx.x;
    const int bh = (n & 7) + 8 * ((n >> 3) % 12);
    int qt, sp, k0t, k1t;
    if constexpr (SPLIT) {
        const int rem = n / 96;            // 0..15, big-work (qt=7) first
        qt = 7 - (rem >> 1);
        sp = rem & 1;
        k0t = sp ? (qt + 1) : 0;
        k1t = sp ? (2 * qt + 2) : (qt + 1);
    } else {
        qt = 7 - n / 96;
        sp = 0; k0t = 0; k1t = 2 * qt + 2;
    }
    const int t = threadIdx.x, lane = t & 63, w = t >> 6;
    const int q5 = lane & 31, h2 = lane >> 5;
    const int srow = t >> 3;              // 0..31
    const int scb = ((t & 7) << 4) ^ ((srow & 7) << 4);
    const char* kb = (const char*)(kg + (size_t)bh * T_ * HD_);
    const char* vb = (const char*)(vg + (size_t)bh * HD_ * T_);

    // Q -> registers (B-frags)
    const int qrow_g = qt * 128 + w * 32 + q5;
    const u16* qrow = qg + (size_t)bh * T_ * HD_ + (size_t)qrow_g * HD_ + h2 * 8;
    bf16x8 qf[4];
#pragma unroll
    for (int kc = 0; kc < 4; kc++)
        qf[kc] = *(const bf16x8*)(qrow + kc * 16);

    // stage first K/V tile of this block's range
#pragma unroll
    for (int s = 0; s < 2; s++) {
        gload16(kb + (size_t)(k0t * 64 + srow + s * 32) * 128 + scb,
                (char*)kld[0] + w * 1024 + s * 4096);
        gload16(vb + (size_t)(srow + s * 32) * 2048 + k0t * 128 + scb,
                (char*)vld[0] + w * 1024 + s * 4096);
    }
    __syncthreads();

    f32x16 acc[2] = {};
    float mst = -1e30f, lst = 0.f;
    const int qmax = qt * 128 + w * 32 + 31;

    for (int kvt = k0t; kvt < k1t; kvt++) {
        const int cur = (kvt - k0t) & 1;
        if (kvt + 1 < k1t) {  // prefetch next K/V tile
#pragma unroll
            for (int s = 0; s < 2; s++) {
                gload16(kb + (size_t)((kvt + 1) * 64 + srow + s * 32) * 128 + scb,
                        (char*)kld[cur ^ 1] + w * 1024 + s * 4096);
                gload16(vb + (size_t)(srow + s * 32) * 2048 + (kvt + 1) * 128 + scb,
                        (char*)vld[cur ^ 1] + w * 1024 + s * 4096);
            }
        }
        if (kvt * 64 <= qmax) {  // tile visible to this wave
            const char* kbase = (const char*)kld[cur];
            const char* vbase = (const char*)vld[cur];
            // S^T = K . Q^T   (exp2-domain scores)
            f32x16 s0 = {}, s1 = {};
            __builtin_amdgcn_s_setprio(1);
#pragma unroll
            for (int kc = 0; kc < 4; kc++) {
                const int r0 = q5, r1 = 32 + q5;
                bf16x8 kf0 = *(const bf16x8*)(kbase + r0 * 128 +
                                              ((kc * 32 + h2 * 16) ^ ((r0 & 7) << 4)));
                bf16x8 kf1 = *(const bf16x8*)(kbase + r1 * 128 +
                                              ((kc * 32 + h2 * 16) ^ ((r1 & 7) << 4)));
                s0 = __builtin_amdgcn_mfma_f32_32x32x16_bf16(kf0, qf[kc], s0, 0, 0, 0);
                s1 = __builtin_amdgcn_mfma_f32_32x32x16_bf16(kf1, qf[kc], s1, 0, 0, 0);
            }
            __builtin_amdgcn_s_setprio(0);
            // causal mask (S^T reg r -> kv = (r&3)+8*(r>>2)+4*h2)
            if (kvt * 64 + 63 > qt * 128 + w * 32) {
                const int kvb0 = kvt * 64 + 4 * h2;
#pragma unroll
                for (int r = 0; r < 16; r++) {
                    const int kvo = (r & 3) + 8 * (r >> 2);
                    if (kvb0 + kvo > qrow_g) s0[r] = -1e30f;
                    if (kvb0 + 32 + kvo > qrow_g) s1[r] = -1e30f;
                }
            }
            // lane-local online softmax; defer-max rescale
            float pmax = fmaxf(redmax16(s0), redmax16(s1));
            pmax = fmaxf(pmax, __shfl_xor(pmax, 32));
            if (!__all(pmax <= mst)) {
                const float mn = fmaxf(mst, pmax);
                const float corr = exp2f(mst - mn);
                mst = mn;
#pragma unroll
                for (int r = 0; r < 16; r++) { acc[0][r] *= corr; acc[1][r] *= corr; }
                lst *= corr;
            }
#pragma unroll
            for (int r = 0; r < 16; r++) {
                s0[r] = exp2f(s0[r] - mst);
                s1[r] = exp2f(s1[r] - mst);
            }
            float rs = redsum16(s0) + redsum16(s1);
            rs += __shfl_xor(rs, 32);
            lst += rs;
            // P -> PV B-frags IN REGISTER (T12)
            u32 pw0[8], pw1[8];
#pragma unroll
            for (int i = 0; i < 4; i++) {
                pw0[i]     = cvtpk(s0[4 * i + 0], s0[4 * i + 1]);
                pw1[i]     = cvtpk(s0[4 * i + 2], s0[4 * i + 3]);
                pw0[i + 4] = cvtpk(s1[4 * i + 0], s1[4 * i + 1]);
                pw1[i + 4] = cvtpk(s1[4 * i + 2], s1[4 * i + 3]);
            }
            bf16x8 pf[4];
#pragma unroll
            for (int m = 0; m < 4; m++) {
                u32 a0 = pw0[2 * m], b0 = pw0[2 * m + 1];
                asm("v_permlane32_swap_b32 %0, %1" : "+v"(a0), "+v"(b0));
                u32 a1 = pw1[2 * m], b1 = pw1[2 * m + 1];
                asm("v_permlane32_swap_b32 %0, %1" : "+v"(a1), "+v"(b1));
                u32x4 wv; wv[0] = a0; wv[1] = a1; wv[2] = b0; wv[3] = b1;
                pf[m] = __builtin_bit_cast(bf16x8, wv);
            }
            // O^T += V^T . P^T
            __builtin_amdgcn_s_setprio(1);
#pragma unroll
            for (int m = 0; m < 4; m++) {
#pragma unroll
                for (int db = 0; db < 2; db++) {
                    const int rd = db * 32 + q5;
                    bf16x8 vf = *(const bf16x8*)(vbase + rd * 128 +
                                                 ((m * 32 + h2 * 16) ^ ((rd & 7) << 4)));
                    acc[db] = __builtin_amdgcn_mfma_f32_32x32x16_bf16(vf, pf[m], acc[db], 0, 0, 0);
                }
            }
            __builtin_amdgcn_s_setprio(0);
        }
        __syncthreads();
    }

    // epilogue: acc[db][r] = O[q=qrow_g][d = db*32 + (r&3)+8*(r>>2)+4*h2]
    if constexpr (SPLIT) {
        const float inv = (lst > 0.f) ? 1.0f / lst : 0.f;  // masked-out half -> 0
        u16* Onp = sp ? On1 : On0;
        u16* orow = Onp + (((size_t)(bh * T_ + qrow_g)) << 6) + 4 * h2;
#pragma unroll
        for (int db = 0; db < 2; db++)
#pragma unroll
            for (int q2 = 0; q2 < 4; q2++) {
                u16x4 pk;
#pragma unroll
                for (int e = 0; e < 4; e++) pk[e] = bfbits(acc[db][q2 * 4 + e] * inv);
                *(u16x4*)(orow + db * 32 + q2 * 8) = pk;
            }
        if (h2 == 0) {  // one lane-group per q-row stores m,l (coalesced)
            const size_t row = (size_t)bh * T_ + qrow_g;
            ml[(size_t)(sp * 2 + 0) * NROW + row] = mst;
            ml[(size_t)(sp * 2 + 1) * NROW + row] = lst;
        }
    } else {
        const int b = bh / H_, h = bh % H_;
        const float inv = 1.0f / lst;
        u16* orow = ao + (size_t)(b * T_ + qrow_g) * C_ + h * 64 + 4 * h2;
#pragma unroll
        for (int db = 0; db < 2; db++)
#pragma unroll
            for (int q2 = 0; q2 < 4; q2++) {
                u16x4 pk;
#pragma unroll
                for (int e = 0; e < 4; e++) pk[e] = bfbits(acc[db][q2 * 4 + e] * inv);
                *(u16x4*)(orow + db * 32 + q2 * 8) = pk;
            }
    }
}

// ---------------- split-merge: O = (w0*On0 + w1*On1), w_s = l_s*2^(m_s-mf) ---
// grid 3072 x 256; idx -> (row, 8-elem chunk). Also does [B,H,T,64]->[B,T,H,64].

__global__ __launch_bounds__(256) void attn_merge_kern(
    const u16* __restrict__ On0, const u16* __restrict__ On1,
    const float* __restrict__ ml, u16* __restrict__ ao) {
    const int idx = blockIdx.x * 256 + threadIdx.x;  // 786432 chunks
    const int row = idx >> 3, c = idx & 7;
    const int bh = row >> 10, tq = row & 1023;
    const int b = bh / H_, h = bh % H_;
    const float m0 = ml[row],            l0 = ml[NROW + row];
    const float m1 = ml[2 * NROW + row], l1 = ml[3 * NROW + row];
    const float mf = fmaxf(m0, m1);
    float w0 = l0 * exp2f(m0 - mf), w1 = l1 * exp2f(m1 - mf);
    const float inv = 1.0f / (w0 + w1);   // w0 > 0 always (kv tile 0 unmasked)
    w0 *= inv; w1 *= inv;
    u16x8 a0 = *(const u16x8*)(On0 + ((size_t)row << 6) + c * 8);
    u16x8 a1 = *(const u16x8*)(On1 + ((size_t)row << 6) + c * 8);
    u16x8 o;
#pragma unroll
    for (int e = 0; e < 8; e++)
        o[e] = bfbits(w0 * bf2f(a0[e]) + w1 * bf2f(a1[e]));
    *(u16x8*)(ao + (size_t)(b * T_ + tq) * C_ + h * 64 + c * 8) = o;
}

// ---------------- launch ----------------

extern "C" void kernel_launch(void* const* d_in, const int* in_sizes, int n_in,
                              void* d_out, int out_size, void* d_ws, size_t ws_size,
                              hipStream_t stream) {
    const float* x     = (const float*)d_in[0];
    // d_in[1] = mask (causal tril) -- structure hard-coded
    const float* Wqkv  = (const float*)d_in[2];
    const float* bqkv  = (const float*)d_in[3];
    const float* Wproj = (const float*)d_in[4];
    const float* bproj = (const float*)d_in[5];
    float* out = (float*)d_out;

    char* ws = (char*)d_ws;
    u16* xb     = (u16*)(ws);                 // 12,582,912 B (On1 reuses this)
    u16* wqkvT  = (u16*)(ws + 12582912);      //  3,538,944 B
    u16* wprojT = (u16*)(ws + 16121856);      //  1,179,648 B
    u16* qw     = (u16*)(ws + 17301504);      // 12,582,912 B  [B,H,T,64]
    u16* kw     = (u16*)(ws + 29884416);      // 12,582,912 B  [B,H,T,64]
    u16* vw     = (u16*)(ws + 42467328);      // 12,582,912 B  [B,H,64,T]
    u16* ao     = (u16*)(ws + 55050240);      // 12,582,912 B  [B*T, C]
    u16* On0    = (u16*)(ws + 67633152);      // 12,582,912 B  split-0 partial O
    float* ml   = (float*)(ws + 80216064);    //  1,572,864 B  [s][m|l][B*H*T]
    // total (split path) = 81,788,928 B; On1 overlays xb (dead after gemm0)
    const bool split = ws_size >= 81788928ULL;

    cvt_all_kern<<<5376, 256, 0, stream>>>(x, xb, Wqkv, Wproj, wqkvT, wprojT);

    gemm_bt_kern<0><<<(M1 / 128) * (N1 / 128), 256, 0, stream>>>(
        xb, wqkvT, bqkv, N1 / 128, qw, kw, vw, nullptr);

    if (split) {
        u16* On1 = xb;  // xb is dead after gemm0
        attn_fwd_kern<1><<<B_ * H_ * (T_ / 128) * 2, 256, 0, stream>>>(
            qw, kw, vw, nullptr, On0, On1, ml);
        attn_merge_kern<<<(NROW * 8) / 256, 256, 0, stream>>>(On0, On1, ml, ao);
    } else {
        attn_fwd_kern<0><<<B_ * H_ * (T_ / 128), 256, 0, stream>>>(
            qw, kw, vw, ao, nullptr, nullptr, nullptr);
    }

    gemm_bt_kern<1><<<(M1 / 128) * (C_ / 128), 256, 0, stream>>>(
        ao, wprojT, bproj, C_ / 128, nullptr, nullptr, nullptr, out);
}

// Round 18
// 102.875 us; speedup vs baseline: 1.0468x; 1.0468x over previous
//
#include <hip/hip_runtime.h>

// SelfAttention fwd: qkv GEMM -> causal flash attention -> proj GEMM, bf16 MFMA.
// B=8 T=1024 C=768 H=12 HD=64.
// FINAL (round-18) = round-14/16 twice-reproduced best config (102.9-103.0us).
// Session A/B ledger:
//   GEMM: 128^2/BK64/single-buf/2-barrier + XCD-chunked swizzle + LDS re-tile
//         epilogue (coalesced u16x8 q/k/vT stores). Regressed alternatives:
//         64KB dbuf (r6), BK32 dbuf (r10/r11), 8-phase port (arithmetic, K=768
//         too shallow + 288-block grid quantization).
//   attn: QBLK=128 / 4 waves / KVBLK=64 dbuf LDS (global_load_lds), swapped
//         32x32 QK^T (lane-local exp2 softmax), in-register P via
//         v_cvt_pk_bf16_f32 + v_permlane32_swap_b32, defer-max rescale,
//         XCD-grouped grid, descending-work order. Regressed alternatives:
//         512-thr (r3), no-LDS direct-global (r12, address divergence),
//         QBLK=64 2-wave (r13), 8-wave shared-KV (r15), kv-split 2-pass (r17).
//   cvt:  single merged dispatch for x->bf16 + both weight transposes.

typedef unsigned short u16;
typedef unsigned int u32;
typedef __bf16 bf16x8 __attribute__((ext_vector_type(8)));
typedef float  f32x4  __attribute__((ext_vector_type(4)));
typedef float  f32x16 __attribute__((ext_vector_type(16)));
typedef unsigned short u16x4 __attribute__((ext_vector_type(4)));
typedef unsigned short u16x8 __attribute__((ext_vector_type(8)));
typedef unsigned int u32x4 __attribute__((ext_vector_type(4)));

#define DEV static __device__ __forceinline__

constexpr int B_ = 8, T_ = 1024, C_ = 768, H_ = 12, HD_ = 64;
constexpr int M1 = B_ * T_;   // 8192
constexpr int N1 = 3 * C_;    // 2304
constexpr int KD = C_;        // 768

DEV u16 f2bf(float f) {
    union { float f; unsigned u; } v; v.f = f;
    unsigned r = v.u + 0x7fffu + ((v.u >> 16) & 1u);   // RNE
    return (u16)(r >> 16);
}

DEV u16 bfbits(float f) {  // native cast -> v_cvt (compiler may pack)
    __bf16 h = (__bf16)f;
    union { __bf16 h; u16 u; } v; v.h = h;
    return v.u;
}

DEV u32 cvtpk(float lo, float hi) {  // pack 2 f32 -> 2 bf16 (RNE), one instr
    u32 r;
    asm("v_cvt_pk_bf16_f32 %0, %1, %2" : "=v"(r) : "v"(lo), "v"(hi));
    return r;
}

DEV void gload16(const void* g, void* l) {
    // async global->LDS, 16B/lane; LDS dest = wave-uniform base + lane*16
    __builtin_amdgcn_global_load_lds(
        (const __attribute__((address_space(1))) unsigned*)g,
        (__attribute__((address_space(3))) unsigned*)l, 16, 0, 0);
}

DEV float redmax16(f32x16 v) {
    float a0 = fmaxf(v[0], v[1]), a1 = fmaxf(v[2], v[3]);
    float a2 = fmaxf(v[4], v[5]), a3 = fmaxf(v[6], v[7]);
    float a4 = fmaxf(v[8], v[9]), a5 = fmaxf(v[10], v[11]);
    float a6 = fmaxf(v[12], v[13]), a7 = fmaxf(v[14], v[15]);
    float b0 = fmaxf(a0, a1), b1 = fmaxf(a2, a3);
    float b2 = fmaxf(a4, a5), b3 = fmaxf(a6, a7);
    return fmaxf(fmaxf(b0, b1), fmaxf(b2, b3));
}
DEV float redsum16(f32x16 v) {
    float a0 = v[0] + v[1], a1 = v[2] + v[3], a2 = v[4] + v[5], a3 = v[6] + v[7];
    float a4 = v[8] + v[9], a5 = v[10] + v[11], a6 = v[12] + v[13], a7 = v[14] + v[15];
    float b0 = a0 + a1, b1 = a2 + a3, b2 = a4 + a5, b3 = a6 + a7;
    return (b0 + b1) + (b2 + b3);
}

// ---------------- merged convert kernel ----------------
// bid < 3072 : x fp32 -> bf16 (8 elems/thread).
// bid >= 3072: weight transpose-convert; wb=bid-3072, bx=wb%96 (n-tile:
//              <72 -> W_qkv N=2304, else W_proj N=768), k0=(wb/96)*32.

__global__ __launch_bounds__(256) void cvt_all_kern(
    const float* __restrict__ x, u16* __restrict__ xb,
    const float* __restrict__ Wq, const float* __restrict__ Wp,
    u16* __restrict__ WqT, u16* __restrict__ WpT) {
    __shared__ float tile[32][33];
    const int bid = blockIdx.x;
    if (bid < 3072) {  // x-convert: 3072*256*8 = M1*C_ elements exactly
        const int i = bid * 256 + threadIdx.x;
        const float4* xf = (const float4*)x;
        float4 a = xf[i * 2], b = xf[i * 2 + 1];
        u16x8 o;
        o[0] = f2bf(a.x); o[1] = f2bf(a.y); o[2] = f2bf(a.z); o[3] = f2bf(a.w);
        o[4] = f2bf(b.x); o[5] = f2bf(b.y); o[6] = f2bf(b.z); o[7] = f2bf(b.w);
        *(u16x8*)(xb + (size_t)i * 8) = o;
        return;
    }
    const int wb = bid - 3072;
    int bx = wb % 96;
    const int k0 = (wb / 96) * 32;
    const float* W; u16* Wt; int N;
    if (bx < N1 / 32) { W = Wq; Wt = WqT; N = N1; }
    else { bx -= N1 / 32; W = Wp; Wt = WpT; N = C_; }
    const int n0 = bx * 32;
    const int tx = threadIdx.x & 31, ty = threadIdx.x >> 5;  // 32 x 8
#pragma unroll
    for (int i = 0; i < 4; i++) {
        int k = ty * 4 + i;
        tile[k][tx] = W[(size_t)(k0 + k) * N + n0 + tx];
    }
    __syncthreads();
#pragma unroll
    for (int i = 0; i < 4; i++) {
        int n = ty * 4 + i;
        Wt[(size_t)(n0 + n) * KD + k0 + tx] = f2bf(tile[tx][n]);
    }
}

// ---------------- GEMM (A [M][K] bf16, Bt [N][K] bf16) ----------------
// 128x128 tile, BK=64, SINGLE-buffer 32KB LDS, 2 barriers/K-step.
// XCD-chunked bijective block swizzle.
// MODE 0: qkv epilogue via LDS re-tile -> coalesced u16x8 stores. q scaled by
// 0.125*log2(e) (attn softmax runs in exp2 domain). MODE 1: fp32 out + bias.

template <int MODE>
__global__ __launch_bounds__(256, 2) void gemm_bt_kern(
    const u16* __restrict__ A, const u16* __restrict__ Bt,
    const float* __restrict__ bias, int nBN,
    u16* __restrict__ qw, u16* __restrict__ kw, u16* __restrict__ vw,
    float* __restrict__ out) {
    __shared__ u16 lds[16384];          // 32KB: A-tile 16KB + B-tile 16KB
    char* LA = (char*)lds;
    char* LB = (char*)lds + 16384;
    // bijective XCD swizzle: same-XCD blocks get a contiguous bid chunk
    const int cpx = gridDim.x >> 3;
    const int bid = (blockIdx.x & 7) * cpx + (blockIdx.x >> 3);
    const int bm = bid / nBN, bn = bid % nBN;
    const int m0 = bm * 128, n0 = bn * 128;
    const int t = threadIdx.x;
    const int lane = t & 63, w = t >> 6;
    const int wr = w >> 1, wc = w & 1;
    const int l15 = lane & 15, lhi = lane >> 4;
    // staging: thread t covers tile-row (t>>3)+s*32, 16B chunk (t&7)
    const int srow = t >> 3;
    const int scb = ((t & 7) << 4) ^ ((srow & 7) << 4);  // pre-swizzled source chunk
    const char* Ab = (const char*)(A + (size_t)(m0 + srow) * KD) + scb;
    const char* Bb = (const char*)(Bt + (size_t)(n0 + srow) * KD) + scb;

    f32x4 acc[4][4] = {};

    for (int k0 = 0; k0 < KD; k0 += 64) {
#pragma unroll
        for (int s = 0; s < 4; s++) {
            gload16(Ab + (size_t)k0 * 2 + (size_t)s * 32 * KD * 2, LA + w * 1024 + s * 4096);
            gload16(Bb + (size_t)k0 * 2 + (size_t)s * 32 * KD * 2, LB + w * 1024 + s * 4096);
        }
        __syncthreads();
#pragma unroll
        for (int kk = 0; kk < 2; kk++) {
            bf16x8 af[4], bfr[4];
#pragma unroll
            for (int i = 0; i < 4; i++) {
                int rowA = wr * 64 + i * 16 + l15;
                af[i] = *(const bf16x8*)(LA + rowA * 128 +
                                         ((kk * 64 + lhi * 16) ^ ((rowA & 7) << 4)));
                int rowB = wc * 64 + i * 16 + l15;
                bfr[i] = *(const bf16x8*)(LB + rowB * 128 +
                                          ((kk * 64 + lhi * 16) ^ ((rowB & 7) << 4)));
            }
#pragma unroll
            for (int fm = 0; fm < 4; fm++)
#pragma unroll
                for (int fn = 0; fn < 4; fn++)
                    acc[fm][fn] = __builtin_amdgcn_mfma_f32_16x16x32_bf16(
                        af[fm], bfr[fn], acc[fm][fn], 0, 0, 0);
        }
        __syncthreads();
    }

    if constexpr (MODE == 1) {
#pragma unroll
        for (int fm = 0; fm < 4; fm++) {
            const int mb = m0 + wr * 64 + fm * 16 + lhi * 4;
#pragma unroll
            for (int fn = 0; fn < 4; fn++) {
                const int n = n0 + wc * 64 + fn * 16 + l15;
                const float bv = bias[n];
#pragma unroll
                for (int r = 0; r < 4; r++)
                    out[(size_t)(mb + r) * C_ + n] = acc[fm][fn][r] + bv;
            }
        }
    } else {
        // epilogue via LDS re-tile (K-loop ended with syncthreads -> LDS free).
        // Block's n-range is uniformly one of q/k/v: bn 0-5 q, 6-11 k, 12-17 v.
        char* TT = (char*)lds;          // 128x128 bf16 = 32KB
        const int typ = bn / 6;         // 0=q, 1=k, 2=v
        const int h0 = (bn % 6) * 2;    // first head covered by this tile
        if (typ < 2) {
            const float sc = (typ == 0) ? 0.125f * 1.44269504f : 1.0f;  // exp2 domain
            // row-major T[row=m][col=n], byte = row*256 + ((col*2)^((row&7)<<5))
#pragma unroll
            for (int fn = 0; fn < 4; fn++) {
                const int col = wc * 64 + fn * 16 + l15;
                const float bv = bias[n0 + col];
#pragma unroll
                for (int fm = 0; fm < 4; fm++) {
                    const int row0 = wr * 64 + fm * 16 + lhi * 4;
#pragma unroll
                    for (int r = 0; r < 4; r++) {
                        const int row = row0 + r;
                        *(u16*)(TT + row * 256 + ((col * 2) ^ ((row & 7) << 5))) =
                            bfbits((acc[fm][fn][r] + bv) * sc);
                    }
                }
            }
            __syncthreads();
            u16* dst = (typ == 0) ? qw : kw;
#pragma unroll
            for (int i = 0; i < 8; i++) {
                const int wk = t + 256 * i;          // 0..2047 16B chunks
                const int m = wk >> 4, c = wk & 15;  // 16 chunks per row
                u16x8 v8 = *(u16x8*)(TT + m * 256 + ((c * 16) ^ ((m & 7) << 5)));
                const int mb = m0 + m, b = mb >> 10, tq = mb & 1023;
                const int h = h0 + (c >> 3), d0 = (c & 7) * 8;
                *(u16x8*)(dst + (((size_t)(b * H_ + h) * T_ + tq) << 6) + d0) = v8;
            }
        } else {
            // transposed T'[col=n][row=m], packed u16x4 (4 consecutive m / lane)
            // byte = col*256 + ((row*2)^((col&7)<<4))
#pragma unroll
            for (int fn = 0; fn < 4; fn++) {
                const int col = wc * 64 + fn * 16 + l15;
                const float bv = bias[n0 + col];
                const int cx = (col & 7) << 4;
#pragma unroll
                for (int fm = 0; fm < 4; fm++) {
                    const int row0 = wr * 64 + fm * 16 + lhi * 4;
                    u16x4 pk;
#pragma unroll
                    for (int r = 0; r < 4; r++) pk[r] = bfbits(acc[fm][fn][r] + bv);
                    *(u16x4*)(TT + col * 256 + ((row0 * 2) ^ cx)) = pk;
                }
            }
            __syncthreads();
#pragma unroll
            for (int i = 0; i < 8; i++) {
                const int wk = t + 256 * i;
                const int col = wk >> 4, ch = wk & 15;
                u16x8 v8 = *(u16x8*)(TT + col * 256 + ((ch * 16) ^ ((col & 7) << 4)));
                const int b = m0 >> 10, tq0 = (m0 & 1023) + ch * 8;
                const int h = h0 + (col >> 6), d = col & 63;
                *(u16x8*)(vw + (((size_t)(b * H_ + h) * HD_ + d) << 10) + tq0) = v8;
            }
        }
    }
}

// ---------------- causal flash attention (swapped 32x32 MFMA) ----------------
// Best-measured attn structure (41.5us): 256 threads / 4 waves, QBLK=128
// (32 q-rows per wave), KVBLK=64, double-buffered LDS K/V via global_load_lds.
// S^T = K.Q^T : lane owns ONE q-row -> lane-local softmax (exp2 domain; q
// pre-scaled by 0.125*log2e). P relayout fully IN-REGISTER via
// v_cvt_pk_bf16_f32 + v_permlane32_swap_b32 (T12) -- no P LDS buffer.
// Defer-max (T13): skip rescale when no new max.
// k [bh][t][64], vT [bh][64][t], out ao [b*t][h*64+d] bf16.

__global__ __launch_bounds__(256, 4) void attn_fwd_kern(
    const u16* __restrict__ qg, const u16* __restrict__ kg,
    const u16* __restrict__ vg, u16* __restrict__ ao) {
    __shared__ u16 kld[2][64 * 64];   // K tile: rows kv, cols k (swizzled)
    __shared__ u16 vld[2][64 * 64];   // V^T tile: rows d, cols kv (swizzled)
    const int n = blockIdx.x;
    const int bh = (n & 7) + 8 * ((n >> 3) % 12);
    const int qt = 7 - n / 96;            // big-work blocks first
    const int t = threadIdx.x, lane = t & 63, w = t >> 6;
    const int q5 = lane & 31, h2 = lane >> 5;
    const int srow = t >> 3;              // 0..31
    const int scb = ((t & 7) << 4) ^ ((srow & 7) << 4);
    const char* kb = (const char*)(kg + (size_t)bh * T_ * HD_);
    const char* vb = (const char*)(vg + (size_t)bh * HD_ * T_);

    // Q -> registers (B-frags): lane covers q-row qt*128+w*32+q5, k chunks
    const int qrow_g = qt * 128 + w * 32 + q5;
    const u16* qrow = qg + (size_t)bh * T_ * HD_ + (size_t)qrow_g * HD_ + h2 * 8;
    bf16x8 qf[4];
#pragma unroll
    for (int kc = 0; kc < 4; kc++)
        qf[kc] = *(const bf16x8*)(qrow + kc * 16);

    // stage K/V tile 0
#pragma unroll
    for (int s = 0; s < 2; s++) {
        gload16(kb + (size_t)(srow + s * 32) * 128 + scb,
                (char*)kld[0] + w * 1024 + s * 4096);
        gload16(vb + (size_t)(srow + s * 32) * 2048 + scb,
                (char*)vld[0] + w * 1024 + s * 4096);
    }
    __syncthreads();

    f32x16 acc[2] = {};
    float mst = -1e30f, lst = 0.f;
    const int qmax = qt * 128 + w * 32 + 31;

    const int ntiles = 2 * qt + 2;
    for (int kvt = 0; kvt < ntiles; kvt++) {
        const int cur = kvt & 1;
        if (kvt + 1 < ntiles) {  // prefetch next K/V tile
#pragma unroll
            for (int s = 0; s < 2; s++) {
                gload16(kb + (size_t)((kvt + 1) * 64 + srow + s * 32) * 128 + scb,
                        (char*)kld[cur ^ 1] + w * 1024 + s * 4096);
                gload16(vb + (size_t)(srow + s * 32) * 2048 + (kvt + 1) * 128 + scb,
                        (char*)vld[cur ^ 1] + w * 1024 + s * 4096);
            }
        }
        if (kvt * 64 <= qmax) {  // tile has at least one visible column for this wave
            const char* kbase = (const char*)kld[cur];
            const char* vbase = (const char*)vld[cur];
            // S^T = K . Q^T   (rows kv, cols q)  -- exp2-domain scores
            f32x16 s0 = {}, s1 = {};
            __builtin_amdgcn_s_setprio(1);
#pragma unroll
            for (int kc = 0; kc < 4; kc++) {
                const int r0 = q5, r1 = 32 + q5;
                bf16x8 kf0 = *(const bf16x8*)(kbase + r0 * 128 +
                                              ((kc * 32 + h2 * 16) ^ ((r0 & 7) << 4)));
                bf16x8 kf1 = *(const bf16x8*)(kbase + r1 * 128 +
                                              ((kc * 32 + h2 * 16) ^ ((r1 & 7) << 4)));
                s0 = __builtin_amdgcn_mfma_f32_32x32x16_bf16(kf0, qf[kc], s0, 0, 0, 0);
                s1 = __builtin_amdgcn_mfma_f32_32x32x16_bf16(kf1, qf[kc], s1, 0, 0, 0);
            }
            __builtin_amdgcn_s_setprio(0);
            // causal mask (S^T reg r -> kv = (r&3)+8*(r>>2)+4*h2)
            if (kvt * 64 + 63 > qt * 128 + w * 32) {
                const int qg_ = qrow_g, kvb0 = kvt * 64 + 4 * h2;
#pragma unroll
                for (int r = 0; r < 16; r++) {
                    const int kvo = (r & 3) + 8 * (r >> 2);
                    if (kvb0 + kvo > qg_) s0[r] = -1e30f;
                    if (kvb0 + 32 + kvo > qg_) s1[r] = -1e30f;
                }
            }
            // lane-local online softmax; defer-max: only rescale on new max
            float pmax = fmaxf(redmax16(s0), redmax16(s1));
            pmax = fmaxf(pmax, __shfl_xor(pmax, 32));
            if (!__all(pmax <= mst)) {
                const float mn = fmaxf(mst, pmax);
                const float corr = exp2f(mst - mn);
                mst = mn;
#pragma unroll
                for (int r = 0; r < 16; r++) { acc[0][r] *= corr; acc[1][r] *= corr; }
                lst *= corr;
            }
#pragma unroll
            for (int r = 0; r < 16; r++) {
                s0[r] = exp2f(s0[r] - mst);
                s1[r] = exp2f(s1[r] - mst);
            }
            float rs = redsum16(s0) + redsum16(s1);
            rs += __shfl_xor(rs, 32);
            lst += rs;
            // P -> PV B-frags IN REGISTER: cvt_pk pairs + permlane32_swap (T12).
            u32 pw0[8], pw1[8];
#pragma unroll
            for (int i = 0; i < 4; i++) {
                pw0[i]     = cvtpk(s0[4 * i + 0], s0[4 * i + 1]);
                pw1[i]     = cvtpk(s0[4 * i + 2], s0[4 * i + 3]);
                pw0[i + 4] = cvtpk(s1[4 * i + 0], s1[4 * i + 1]);
                pw1[i + 4] = cvtpk(s1[4 * i + 2], s1[4 * i + 3]);
            }
            bf16x8 pf[4];
#pragma unroll
            for (int m = 0; m < 4; m++) {
                u32 a0 = pw0[2 * m], b0 = pw0[2 * m + 1];
                asm("v_permlane32_swap_b32 %0, %1" : "+v"(a0), "+v"(b0));
                u32 a1 = pw1[2 * m], b1 = pw1[2 * m + 1];
                asm("v_permlane32_swap_b32 %0, %1" : "+v"(a1), "+v"(b1));
                u32x4 wv; wv[0] = a0; wv[1] = a1; wv[2] = b0; wv[3] = b1;
                pf[m] = __builtin_bit_cast(bf16x8, wv);
            }
            // O^T += V^T . P^T
            __builtin_amdgcn_s_setprio(1);
#pragma unroll
            for (int m = 0; m < 4; m++) {
#pragma unroll
                for (int db = 0; db < 2; db++) {
                    const int rd = db * 32 + q5;
                    bf16x8 vf = *(const bf16x8*)(vbase + rd * 128 +
                                                 ((m * 32 + h2 * 16) ^ ((rd & 7) << 4)));
                    acc[db] = __builtin_amdgcn_mfma_f32_32x32x16_bf16(vf, pf[m], acc[db], 0, 0, 0);
                }
            }
            __builtin_amdgcn_s_setprio(0);
        }
        __syncthreads();  // prefetched tile ready; all waves done with buf[cur]
    }

    // epilogue: acc[db][r] = O[q = qrow_g][d = db*32 + (r&3) + 8*(r>>2) + 4*h2]
    const int b = bh / H_, h = bh % H_;
    const float inv = 1.0f / lst;
    u16* orow = ao + (size_t)(b * T_ + qrow_g) * C_ + h * 64 + 4 * h2;
#pragma unroll
    for (int db = 0; db < 2; db++)
#pragma unroll
        for (int q2 = 0; q2 < 4; q2++) {
            u16x4 pk;
#pragma unroll
            for (int e = 0; e < 4; e++) pk[e] = bfbits(acc[db][q2 * 4 + e] * inv);
            *(u16x4*)(orow + db * 32 + q2 * 8) = pk;
        }
}

// ---------------- launch ----------------

extern "C" void kernel_launch(void* const* d_in, const int* in_sizes, int n_in,
                              void* d_out, int out_size, void* d_ws, size_t ws_size,
                              hipStream_t stream) {
    const float* x     = (const float*)d_in[0];
    // d_in[1] = mask (causal tril) -- structure hard-coded
    const float* Wqkv  = (const float*)d_in[2];
    const float* bqkv  = (const float*)d_in[3];
    const float* Wproj = (const float*)d_in[4];
    const float* bproj = (const float*)d_in[5];
    float* out = (float*)d_out;

    char* ws = (char*)d_ws;
    u16* xb     = (u16*)(ws);                 // 12,582,912 B
    u16* wqkvT  = (u16*)(ws + 12582912);      //  3,538,944 B
    u16* wprojT = (u16*)(ws + 16121856);      //  1,179,648 B
    u16* qw     = (u16*)(ws + 17301504);      // 12,582,912 B  [B,H,T,64] (pre-scaled)
    u16* kw     = (u16*)(ws + 29884416);      // 12,582,912 B  [B,H,T,64]
    u16* vw     = (u16*)(ws + 42467328);      // 12,582,912 B  [B,H,64,T] (transposed)
    u16* ao     = (u16*)(ws + 55050240);      // 12,582,912 B  [B*T, C]

    // merged converts: 3072 x-blocks + 96*24 weight-blocks = 5376
    cvt_all_kern<<<5376, 256, 0, stream>>>(x, xb, Wqkv, Wproj, wqkvT, wprojT);

    gemm_bt_kern<0><<<(M1 / 128) * (N1 / 128), 256, 0, stream>>>(
        xb, wqkvT, bqkv, N1 / 128, qw, kw, vw, nullptr);

    attn_fwd_kern<<<B_ * H_ * (T_ / 128), 256, 0, stream>>>(qw, kw, vw, ao);

    gemm_bt_kern<1><<<(M1 / 128) * (C_ / 128), 256, 0, stream>>>(
        ao, wprojT, bproj, C_ / 128, nullptr, nullptr, nullptr, out);
}